// Round 7
// baseline (160.782 us; speedup 1.0000x reference)
//
#include <hip/hip_runtime.h>
#include <hip/hip_bf16.h>

typedef __hip_bfloat16 bf16;
typedef __attribute__((ext_vector_type(8))) short bf16x8;
typedef __attribute__((ext_vector_type(4))) float f32x4;
#define DIM 128
#define BK 64       // fallback bucket slots/node
#define PCAP 4096   // partition edge capacity (mean 1024, ~96 sigma)
#define CHUNK 4096  // pass-1 edges per block
#define EPT2 4      // edges per thread in pass 1 (1024 threads)

__device__ __forceinline__ float bfbits(unsigned short u) {
    return __uint_as_float(((unsigned)u) << 16);
}
__device__ __forceinline__ unsigned short f2bf(float f) {
    bf16 h = __float2bfloat16(f);
    return *(unsigned short*)&h;
}
__device__ __forceinline__ void load8(const void* p, int is32, size_t off, float* f) {
    if (is32) {
        const float* q = (const float*)p + off;
        float4 a = *(const float4*)q;
        float4 b = *(const float4*)(q + 4);
        f[0] = a.x; f[1] = a.y; f[2] = a.z; f[3] = a.w;
        f[4] = b.x; f[5] = b.y; f[6] = b.z; f[7] = b.w;
    } else {
        uint4 v = *(const uint4*)((const unsigned short*)p + off);
        const unsigned int* w = (const unsigned int*)&v;
#pragma unroll
        for (int i = 0; i < 4; i++) {
            f[2 * i]     = __uint_as_float(w[i] << 16);
            f[2 * i + 1] = __uint_as_float(w[i] & 0xffff0000u);
        }
    }
}
__device__ __forceinline__ int read_idx(const void* p, int is64, int e) {
    return is64 ? (int)((const long long*)p)[e] : ((const int*)p)[e];
}

// ---------------- init: zero counters + dtype detect ----------------
__device__ __forceinline__ int is_fp32_wave(const unsigned int* p, int lane) {
    unsigned w = p[lane];
    unsigned low = w & 0xFFFFu;
    unsigned ex = (low >> 7) & 0xFFu;
    bool hit = (ex >= 90u && ex <= 140u) || low == 0u || low == 0x8000u;
    unsigned long long m = __ballot(hit);
    return (2 * __popcll(m) < 64) ? 1 : 0;
}
__global__ void init_kernel(const unsigned int* __restrict__ src,
                            const unsigned int* __restrict__ feat,
                            const unsigned int* __restrict__ wn,
                            const unsigned int* __restrict__ wsm,
                            const unsigned int* __restrict__ bias,
                            int* __restrict__ flags, int* __restrict__ cnt, int Z) {
    int i = blockIdx.x * blockDim.x + threadIdx.x;
    if (i < Z) cnt[i] = 0;
    if (blockIdx.x == 0 && threadIdx.x < 64) {
        int lane = threadIdx.x;
        unsigned long long m = __ballot(src[1 + 2 * lane] != 0u);
        int f1 = is_fp32_wave(feat, lane);
        int f2 = is_fp32_wave(wn, lane);
        int f3 = is_fp32_wave(wsm, lane);
        int f4 = is_fp32_wave(bias, lane);
        if (lane == 0) {
            flags[0] = (m == 0ull) ? 1 : 0;
            flags[1] = f1; flags[2] = f2; flags[3] = f3; flags[4] = f4;
        }
    }
}

// ---------------- pass 1: radix partition by dst>>6, 1024 threads ----------------
// 196 blocks on 256 CUs -> duration == one block's serial latency. 1024 thr
// (vs 256) cuts the histogram/reorder/copyout critical path ~4x; scan is 1
// bin/thread (nparts<=1024). Same global-atomic count (the cheap part).
__global__ __launch_bounds__(1024) void part_kernel(
    const void* __restrict__ srcv, const void* __restrict__ dstv,
    const int* __restrict__ flags, int* __restrict__ gcnt,
    unsigned* __restrict__ pbuf,
    const float* __restrict__ featf, unsigned short* __restrict__ wsbf,
    int E, int N, int eblocks, int total8, int nparts, int cstride) {
    __shared__ int hist[1024];
    __shared__ int bstart[1024];
    __shared__ int gbase[1024];
    __shared__ int tsum[1024];
    __shared__ unsigned stage[CHUNK];

    int b = blockIdx.x;
    int t = threadIdx.x;

    if (b >= eblocks) {              // feat fp32 -> bf16 convert (grid-stride)
        if (!flags[1]) return;
        for (int i = (b - eblocks) * 1024 + t; i < total8; i += cstride) {
            size_t e = (size_t)i * 8;
            float4 a = *(const float4*)(featf + e);
            float4 bb = *(const float4*)(featf + e + 4);
            unsigned short u[8] = {f2bf(a.x), f2bf(a.y), f2bf(a.z), f2bf(a.w),
                                   f2bf(bb.x), f2bf(bb.y), f2bf(bb.z), f2bf(bb.w)};
            *(uint4*)(wsbf + e) = *(uint4*)u;
        }
        return;
    }

    int is64 = flags[0];
    hist[t] = 0;
    __syncthreads();

    // load + pack + LDS histogram
    unsigned v[EPT2];
    int base = b * CHUNK;
#pragma unroll
    for (int j = 0; j < EPT2; j++) {
        int e = base + j * 1024 + t;
        unsigned val = 0xFFFFFFFFu;
        if (e < E) {
            int s = read_idx(srcv, is64, e);
            int d = read_idx(dstv, is64, e);
            if ((unsigned)s < (unsigned)N && (unsigned)d < (unsigned)N)
                val = ((unsigned)d << 16) | (unsigned)s;
        }
        v[j] = val;
        if (val != 0xFFFFFFFFu) atomicAdd(&hist[val >> 22], 1);
    }
    __syncthreads();

    // inclusive scan over 1024 (1 bin/thread; t>=nparts contributes 0)
    int h = (t < nparts) ? hist[t] : 0;
    tsum[t] = h;
    __syncthreads();
    for (int off = 1; off < 1024; off <<= 1) {
        int x = (t >= off) ? tsum[t - off] : 0;
        __syncthreads();
        tsum[t] += x;
        __syncthreads();
    }
    int tot = tsum[1023];
    int run = (t > 0) ? tsum[t - 1] : 0;     // exclusive prefix
    if (t < nparts) {
        bstart[t] = run;
        hist[t] = run;                        // cursor
        gbase[t] = h ? atomicAdd(&gcnt[t], h) : 0;   // reserve global run
    }
    __syncthreads();

    // reorder through LDS
#pragma unroll
    for (int j = 0; j < EPT2; j++) {
        unsigned val = v[j];
        if (val != 0xFFFFFFFFu) {
            int bin = val >> 22;
            int pos = atomicAdd(&hist[bin], 1);
            stage[pos] = val;
        }
    }
    __syncthreads();

    // coalesced per-run copy-out
    for (int pp = t; pp < tot; pp += 1024) {
        unsigned val = stage[pp];
        int bin = val >> 22;
        unsigned off = (unsigned)(gbase[bin] + (pp - bstart[bin]));
        if (off < PCAP) pbuf[(size_t)bin * PCAP + off] = val;
    }
}

// ---------------- pass 2: merged list-build + gather + MFMA GEMM ----------------
// One block per partition (64 nodes = 4 output tiles, 4 waves). Phase-sequenced
// 64KB LDS union: [cnt|list] during build+gather, then W fragments for the GEMM.
// Kills the separate gemm launch (391 under-subscribed blocks + tail); hn is
// written and re-read by the SAME wave (wave wv owns nodes wv*16..+15) so the
// out round-trip stays L2-hot and race-free.
__global__ __launch_bounds__(256) void ggemm_kernel(
    const void* __restrict__ feat, const unsigned short* __restrict__ wsbf,
    const unsigned* __restrict__ pbuf, const int* __restrict__ gcnt,
    const void* __restrict__ Wn, const void* __restrict__ Ws,
    const void* __restrict__ bias, void* __restrict__ out,
    int N, const int* __restrict__ flags) {
    __shared__ short ldsb[4096 * 8];   // 64 KB union

    int* cntp = (int*)ldsb;                                   // 64 ints (256 B)
    unsigned short (*list)[64] = (unsigned short (*)[64])(ldsb + 128);  // 8 KB

    int t = threadIdx.x;
    int lane = t & 63;
    int wv = t >> 6;
    int p = blockIdx.x;
    int nbase = p << 6;
    int feat32 = flags[1], wn32 = flags[2], ws32 = flags[3], bs32 = flags[4];
    const unsigned short* sb = feat32 ? wsbf : (const unsigned short*)feat;
    char* hbase = (char*)out;
    size_t hrow = feat32 ? 512 : 256;
    size_t hoff = feat32 ? 256 : 0;

    // phase 1: zero counters
    if (t < 64) cntp[t] = 0;
    __syncthreads();

    // phase 2: build per-node lists (LDS atomics)
    int ec = gcnt[p];
    if (ec > PCAP) ec = PCAP;
    for (int i = t; i < ec; i += 256) {
        unsigned val = pbuf[(size_t)p * PCAP + i];
        int local = (int)(val >> 16) - nbase;      // 0..63 by construction
        int pos = atomicAdd(&cntp[local], 1);
        if (pos < 64) list[local][pos] = (unsigned short)(val & 0xFFFFu);
    }
    __syncthreads();

    // phase 3: widened gather (dwordx4; each 16-lane group a different row)
    int grp = lane >> 4;
    int li = lane & 15;
    for (int q = 0; q < 16; q++) {
        int local = wv * 16 + q;
        int node = nbase + local;
        if (node >= N) break;
        int deg = cntp[local];
        int use = deg < 64 ? deg : 64;

        float acc[8];
#pragma unroll
        for (int i = 0; i < 8; i++) acc[i] = 0.f;

        for (int k = 0; k < use; k += 16) {
            uint4 v[4];
            float wgt[4];
#pragma unroll
            for (int j = 0; j < 4; j++) {
                int r = k + j * 4 + grp;
                wgt[j] = (r < use) ? 1.0f : 0.0f;
                int rc = (r < use) ? r : (use - 1);   // clamp: dup load hits cache
                int s = list[local][rc];
                v[j] = *(const uint4*)(sb + (size_t)s * DIM + li * 8);
            }
#pragma unroll
            for (int j = 0; j < 4; j++) {
                const unsigned* w = (const unsigned*)&v[j];
#pragma unroll
                for (int i = 0; i < 4; i++) {
                    acc[2 * i]     = fmaf(wgt[j], __uint_as_float(w[i] << 16), acc[2 * i]);
                    acc[2 * i + 1] = fmaf(wgt[j], __uint_as_float(w[i] & 0xffff0000u), acc[2 * i + 1]);
                }
            }
        }
#pragma unroll
        for (int i = 0; i < 8; i++) {
            acc[i] += __shfl_xor(acc[i], 16);
            acc[i] += __shfl_xor(acc[i], 32);
        }
        float rd = 1.0f / fmaxf((float)deg, 1.0f);
        if (grp == 0) {
            unsigned short u[8];
#pragma unroll
            for (int i = 0; i < 8; i++) u[i] = f2bf(acc[i] * rd);
            *(uint4*)(hbase + (size_t)node * hrow + hoff + (size_t)li * 16) = *(uint4*)u;
        }
    }
    __syncthreads();   // lists consumed; hn stores drained (vmcnt 0 at barrier)

    // phase 4: stage W over the union (overwrites cnt/list)
    for (int f = t; f < 4096; f += 256) {
        int tj = f >> 9, ks = (f >> 6) & 7, ln = f & 63;
        int j = tj * 16 + (ln & 15);
        int kk = ks * 32 + (ln >> 4) * 8;
        float w[8];
        if (kk < DIM) load8(Ws, ws32, (size_t)j * DIM + kk, w);
        else          load8(Wn, wn32, (size_t)j * DIM + (kk - DIM), w);
        unsigned short u[8];
#pragma unroll
        for (int i = 0; i < 8; i++) u[i] = f2bf(w[i]);
        *(uint4*)(ldsb + (size_t)f * 8) = *(uint4*)u;
    }
    __syncthreads();

    // phase 5: GEMM — wave wv handles tile rows [nbase+wv*16, +16)
    const bf16x8* bfrag = (const bf16x8*)ldsb;
    int quad = lane >> 4;

    float bcol[8];
#pragma unroll
    for (int tj = 0; tj < 8; tj++) {
        int col = tj * 16 + (lane & 15);
        bcol[tj] = bs32 ? ((const float*)bias)[col]
                        : bfbits(((const unsigned short*)bias)[col]);
    }

    int tb = nbase + wv * 16;
    int arow = tb + (lane & 15);
    if (arow >= N) arow = N - 1;

    bf16x8 afr[8];
#pragma unroll
    for (int ks = 0; ks < 4; ks++) {        // self (bf16: native or wsbf)
        int kk = ks * 32 + quad * 8;
        afr[ks] = *(const bf16x8*)(sb + (size_t)arow * DIM + kk);
    }
#pragma unroll
    for (int ks = 4; ks < 8; ks++) {        // neigh scratch in out (L2-hot)
        int kk = (ks - 4) * 32 + quad * 8;
        afr[ks] = *(const bf16x8*)(hbase + (size_t)arow * hrow + hoff + (size_t)kk * 2);
    }

    f32x4 acc[8];
#pragma unroll
    for (int tj = 0; tj < 8; tj++)
        acc[tj] = (f32x4){bcol[tj], bcol[tj], bcol[tj], bcol[tj]};

#pragma unroll
    for (int tj = 0; tj < 8; tj++) {
#pragma unroll
        for (int ks = 0; ks < 8; ks++) {
            acc[tj] = __builtin_amdgcn_mfma_f32_16x16x32_bf16(
                afr[ks], bfrag[(tj * 8 + ks) * 64 + lane], acc[tj], 0, 0, 0);
        }
    }

#pragma unroll
    for (int tj = 0; tj < 8; tj++) {
        int col = tj * 16 + (lane & 15);
#pragma unroll
        for (int r = 0; r < 4; r++) {
            int row = tb + quad * 4 + r;
            if (row < N) {
                size_t idx = (size_t)row * DIM + col;
                if (feat32) ((float*)out)[idx] = acc[tj][r];
                else ((unsigned short*)out)[idx] = f2bf(acc[tj][r]);
            }
        }
    }
}

// ---------------- fallback: round-0 bucketing (device atomics) ----------------
__global__ void buckcvt_kernel(const void* __restrict__ srcv, const void* __restrict__ dstv,
                               const int* __restrict__ flags, int* __restrict__ cnt,
                               unsigned short* __restrict__ b16, int* __restrict__ b32,
                               const float* __restrict__ featf,
                               unsigned short* __restrict__ wsbf,
                               int E, int N, int eblocks, int total8, int use16, int ws_ok) {
    int b = blockIdx.x;
    if (b < eblocks) {
        int e = b * 256 + threadIdx.x;
        if (e >= E) return;
        int is64 = flags[0];
        int s = read_idx(srcv, is64, e);
        int d = read_idx(dstv, is64, e);
        if ((unsigned)s >= (unsigned)N || (unsigned)d >= (unsigned)N) return;
        int pos = atomicAdd(&cnt[d], 1);
        if (pos < BK) {
            if (use16) b16[(size_t)d * BK + pos] = (unsigned short)s;
            else       b32[(size_t)d * BK + pos] = s;
        }
    } else {
        if (!flags[1] || !ws_ok) return;
        int i = (b - eblocks) * 256 + threadIdx.x;
        if (i >= total8) return;
        size_t e = (size_t)i * 8;
        float4 a = *(const float4*)(featf + e);
        float4 bb = *(const float4*)(featf + e + 4);
        unsigned short u[8] = {f2bf(a.x), f2bf(a.y), f2bf(a.z), f2bf(a.w),
                               f2bf(bb.x), f2bf(bb.y), f2bf(bb.z), f2bf(bb.w)};
        *(uint4*)(wsbf + e) = *(uint4*)u;
    }
}

__global__ __launch_bounds__(256) void gather_kernel(
    const void* __restrict__ feat, const unsigned short* __restrict__ wsbf,
    const unsigned short* __restrict__ b16, const int* __restrict__ b32,
    const int* __restrict__ cnt, void* __restrict__ dout,
    int N, const int* __restrict__ flags, int use16, int ws_ok) {
    int t = threadIdx.x;
    int lane = t & 63;
    int wv = t >> 6;
    int node = blockIdx.x * 4 + wv;
    if (node >= N) return;
    int feat32 = flags[1];
    int bfmode = (!feat32) || ws_ok;
    const unsigned short* sb = feat32 ? wsbf : (const unsigned short*)feat;
    const float* ff = (const float*)feat;

    int deg = __builtin_amdgcn_readfirstlane(cnt[node]);
    int use = deg < BK ? deg : BK;
    int idxv;
    if (use16) idxv = b16[(size_t)node * BK + (lane < use ? lane : 0)];
    else       idxv = b32[(size_t)node * BK + (lane < use ? lane : 0)];

    float a0 = 0.f, a1 = 0.f;
    int k = 0;
    if (bfmode) {
        for (; k + 8 <= use; k += 8) {
            int ss[8];
#pragma unroll
            for (int j = 0; j < 8; j++) ss[j] = __shfl(idxv, k + j);
            unsigned uu[8];
#pragma unroll
            for (int j = 0; j < 8; j++)
                uu[j] = *(const unsigned*)(sb + (size_t)ss[j] * DIM + lane * 2);
#pragma unroll
            for (int j = 0; j < 8; j++) {
                a0 += bfbits((unsigned short)uu[j]);
                a1 += bfbits((unsigned short)(uu[j] >> 16));
            }
        }
        for (; k < use; k++) {
            int s = __shfl(idxv, k);
            unsigned u = *(const unsigned*)(sb + (size_t)s * DIM + lane * 2);
            a0 += bfbits((unsigned short)u);
            a1 += bfbits((unsigned short)(u >> 16));
        }
    } else {
        for (; k + 4 <= use; k += 4) {
            int s0 = __shfl(idxv, k),     s1 = __shfl(idxv, k + 1);
            int s2 = __shfl(idxv, k + 2), s3 = __shfl(idxv, k + 3);
            float2 v0 = *(const float2*)(ff + (size_t)s0 * DIM + lane * 2);
            float2 v1 = *(const float2*)(ff + (size_t)s1 * DIM + lane * 2);
            float2 v2 = *(const float2*)(ff + (size_t)s2 * DIM + lane * 2);
            float2 v3 = *(const float2*)(ff + (size_t)s3 * DIM + lane * 2);
            a0 += (v0.x + v1.x) + (v2.x + v3.x);
            a1 += (v0.y + v1.y) + (v2.y + v3.y);
        }
        for (; k < use; k++) {
            int s = __shfl(idxv, k);
            float2 v = *(const float2*)(ff + (size_t)s * DIM + lane * 2);
            a0 += v.x; a1 += v.y;
        }
    }

    float rd = 1.0f / fmaxf((float)deg, 1.0f);
    unsigned up = ((unsigned)f2bf(a1 * rd) << 16) | (unsigned)f2bf(a0 * rd);
    size_t ob = feat32 ? ((size_t)node * 512 + 256 + (size_t)lane * 4)
                       : ((size_t)node * 256 + (size_t)lane * 4);
    *(unsigned*)((char*)dout + ob) = up;
}

// ---------------- fallback MFMA GEMM (dual-tile) ----------------
#define TPW 2
__global__ __launch_bounds__(256) void gemm_kernel(
    const void* __restrict__ feat, const unsigned short* __restrict__ wsbf,
    const void* __restrict__ Wn, const void* __restrict__ Ws,
    const void* __restrict__ bias, void* __restrict__ out,
    int N, const int* __restrict__ flags, int ws_ok) {
    __shared__ short ldsb[4096 * 8];   // 64 KB

    int t = threadIdx.x;
    int lane = t & 63;
    int wv = t >> 6;
    int feat32 = flags[1], wn32 = flags[2], ws32 = flags[3], bs32 = flags[4];
    int bfmode = (!feat32) || ws_ok;

    for (int f = t; f < 4096; f += 256) {
        int tj = f >> 9, ks = (f >> 6) & 7, ln = f & 63;
        int j = tj * 16 + (ln & 15);
        int kk = ks * 32 + (ln >> 4) * 8;
        float w[8];
        if (kk < DIM) load8(Ws, ws32, (size_t)j * DIM + kk, w);
        else          load8(Wn, wn32, (size_t)j * DIM + (kk - DIM), w);
        unsigned short u[8];
#pragma unroll
        for (int i = 0; i < 8; i++) u[i] = f2bf(w[i]);
        *(uint4*)(ldsb + (size_t)f * 8) = *(uint4*)u;
    }
    __syncthreads();

    const bf16x8* bfrag = (const bf16x8*)ldsb;

    float bcol[8];
#pragma unroll
    for (int tj = 0; tj < 8; tj++) {
        int col = tj * 16 + (lane & 15);
        bcol[tj] = bs32 ? ((const float*)bias)[col]
                        : bfbits(((const unsigned short*)bias)[col]);
    }

    int quad = lane >> 4;
    int NT = (N + 15) >> 4;
    int gw = blockIdx.x * 4 + wv;

    const unsigned short* sb = feat32 ? wsbf : (const unsigned short*)feat;
    const char* hbase = (const char*)out;
    size_t hrow = feat32 ? 512 : 256;
    size_t hoff = feat32 ? 256 : 0;

    int tile0 = gw * TPW;
    int tile1 = tile0 + 1;
    if (tile0 >= NT) return;
    int has1 = (tile1 < NT);
    int tb0 = tile0 * 16;
    int tb1 = has1 ? tile1 * 16 : tb0;

    int arow0 = tb0 + (lane & 15); if (arow0 >= N) arow0 = N - 1;
    int arow1 = tb1 + (lane & 15); if (arow1 >= N) arow1 = N - 1;

    bf16x8 afr0[8], afr1[8];
#pragma unroll
    for (int ks = 0; ks < 4; ks++) {
        int kk = ks * 32 + quad * 8;
        if (bfmode) {
            afr0[ks] = *(const bf16x8*)(sb + (size_t)arow0 * DIM + kk);
            afr1[ks] = *(const bf16x8*)(sb + (size_t)arow1 * DIM + kk);
        } else {
            float av[8]; unsigned short u[8];
            load8(feat, 1, (size_t)arow0 * DIM + kk, av);
#pragma unroll
            for (int i = 0; i < 8; i++) u[i] = f2bf(av[i]);
            afr0[ks] = *(bf16x8*)u;
            load8(feat, 1, (size_t)arow1 * DIM + kk, av);
#pragma unroll
            for (int i = 0; i < 8; i++) u[i] = f2bf(av[i]);
            afr1[ks] = *(bf16x8*)u;
        }
    }
#pragma unroll
    for (int ks = 4; ks < 8; ks++) {
        int kk = (ks - 4) * 32 + quad * 8;
        afr0[ks] = *(const bf16x8*)(hbase + (size_t)arow0 * hrow + hoff + (size_t)kk * 2);
        afr1[ks] = *(const bf16x8*)(hbase + (size_t)arow1 * hrow + hoff + (size_t)kk * 2);
    }

    f32x4 acc0[8], acc1[8];
#pragma unroll
    for (int tj = 0; tj < 8; tj++) {
        acc0[tj] = (f32x4){bcol[tj], bcol[tj], bcol[tj], bcol[tj]};
        acc1[tj] = acc0[tj];
    }

#pragma unroll
    for (int tj = 0; tj < 8; tj++) {
#pragma unroll
        for (int ks = 0; ks < 8; ks++) {
            bf16x8 bf = bfrag[(tj * 8 + ks) * 64 + lane];
            acc0[tj] = __builtin_amdgcn_mfma_f32_16x16x32_bf16(afr0[ks], bf, acc0[tj], 0, 0, 0);
            acc1[tj] = __builtin_amdgcn_mfma_f32_16x16x32_bf16(afr1[ks], bf, acc1[tj], 0, 0, 0);
        }
    }

#pragma unroll
    for (int tj = 0; tj < 8; tj++) {
        int col = tj * 16 + (lane & 15);
#pragma unroll
        for (int r = 0; r < 4; r++) {
            int row0 = tb0 + quad * 4 + r;
            if (row0 < N) {
                size_t idx = (size_t)row0 * DIM + col;
                if (feat32) ((float*)out)[idx] = acc0[tj][r];
                else ((unsigned short*)out)[idx] = f2bf(acc0[tj][r]);
            }
            if (has1) {
                int row1 = tb1 + quad * 4 + r;
                if (row1 < N) {
                    size_t idx = (size_t)row1 * DIM + col;
                    if (feat32) ((float*)out)[idx] = acc1[tj][r];
                    else ((unsigned short*)out)[idx] = f2bf(acc1[tj][r]);
                }
            }
        }
    }
}

extern "C" void kernel_launch(void* const* d_in, const int* in_sizes, int n_in,
                              void* d_out, int out_size, void* d_ws, size_t ws_size,
                              hipStream_t stream) {
    const void* feat = d_in[0];
    const void* src  = d_in[1];
    const void* dst  = d_in[2];
    const void* Wn   = d_in[3];
    const void* Ws   = d_in[4];
    const void* bias = d_in[5];

    const int N = in_sizes[0] / DIM;
    const int E = in_sizes[1];
    const int use16 = (N <= 65535) ? 1 : 0;
    const int total8 = N * DIM / 8;
    int* flags = (int*)d_ws;

    // fast-path layout: flags(64B) | gcnt(nparts int) | pbuf(nparts*PCAP u32) | wsbf
    const int nparts = (N + 63) >> 6;
    size_t pbuf_off = (64 + (size_t)nparts * 4 + 255) & ~(size_t)255;
    size_t wsf_off  = (pbuf_off + (size_t)nparts * PCAP * 4 + 255) & ~(size_t)255;
    size_t need_f   = wsf_off + (size_t)N * DIM * 2;
    const int FAST = (use16 && nparts <= 1024 && ws_size >= need_f) ? 1 : 0;

    if (FAST) {
        int* gcnt = (int*)((char*)d_ws + 64);
        unsigned* pbuf = (unsigned*)((char*)d_ws + pbuf_off);
        unsigned short* wsbf = (unsigned short*)((char*)d_ws + wsf_off);

        init_kernel<<<(nparts + 255) / 256, 256, 0, stream>>>(
            (const unsigned int*)src, (const unsigned int*)feat, (const unsigned int*)Wn,
            (const unsigned int*)Ws, (const unsigned int*)bias, flags, gcnt, nparts);

        int eb = (E + CHUNK - 1) / CHUNK;
        int cb = (total8 + 1023) / 1024;
        if (cb > 1024) cb = 1024;                 // grid-stride convert
        part_kernel<<<eb + cb, 1024, 0, stream>>>(
            src, dst, flags, gcnt, pbuf, (const float*)feat, wsbf,
            E, N, eb, total8, nparts, cb * 1024);

        ggemm_kernel<<<nparts, 256, 0, stream>>>(
            feat, wsbf, pbuf, gcnt, Wn, Ws, bias, d_out, N, flags);
        return;
    }

    // ---------- fallback: round-0 proven path ----------
    const size_t esz = use16 ? 2 : 4;
    int* cnt = flags + 16;
    unsigned short* b16 = (unsigned short*)(cnt + N);
    int* b32 = (int*)(cnt + N);
    size_t bucket_bytes = (size_t)N * BK * esz;
    size_t bf_off = (64 + (size_t)N * 4 + bucket_bytes + 15) & ~(size_t)15;
    unsigned short* wsbf = (unsigned short*)((char*)d_ws + bf_off);
    size_t need = bf_off + (size_t)N * DIM * 2;
    int ws_ok = (ws_size >= need) ? 1 : 0;

    init_kernel<<<(N + 255) / 256, 256, 0, stream>>>(
        (const unsigned int*)src, (const unsigned int*)feat, (const unsigned int*)Wn,
        (const unsigned int*)Ws, (const unsigned int*)bias, flags, cnt, N);

    int eblocks = (E + 255) / 256;
    int cblocks = ws_ok ? (total8 + 255) / 256 : 0;
    buckcvt_kernel<<<eblocks + cblocks, 256, 0, stream>>>(
        src, dst, flags, cnt, b16, b32, (const float*)feat, wsbf,
        E, N, eblocks, total8, use16, ws_ok);

    gather_kernel<<<(N + 3) / 4, 256, 0, stream>>>(
        feat, wsbf, b16, b32, cnt, d_out, N, flags, use16, ws_ok);

    int NT = (N + 15) / 16;
    int gwaves = (NT + TPW - 1) / TPW;
    gemm_kernel<<<(gwaves + 3) / 4, 256, 0, stream>>>(
        feat, wsbf, Wn, Ws, bias, d_out, N, flags, ws_ok);
}

// Round 8
// 136.224 us; speedup vs baseline: 1.1803x; 1.1803x over previous
//
#include <hip/hip_runtime.h>
#include <hip/hip_bf16.h>

typedef __hip_bfloat16 bf16;
typedef __attribute__((ext_vector_type(8))) short bf16x8;
typedef __attribute__((ext_vector_type(4))) float f32x4;
#define DIM 128
#define BK 64       // fallback bucket slots/node
#define PCAP 4096   // partition edge capacity (mean 1024, ~96 sigma)
#define CHUNK 4096  // pass-1 edges per block
#define EPT2 4      // edges per thread in pass 1 (1024 threads)

__device__ __forceinline__ float bfbits(unsigned short u) {
    return __uint_as_float(((unsigned)u) << 16);
}
__device__ __forceinline__ unsigned short f2bf(float f) {
    bf16 h = __float2bfloat16(f);
    return *(unsigned short*)&h;
}
__device__ __forceinline__ void load8(const void* p, int is32, size_t off, float* f) {
    if (is32) {
        const float* q = (const float*)p + off;
        float4 a = *(const float4*)q;
        float4 b = *(const float4*)(q + 4);
        f[0] = a.x; f[1] = a.y; f[2] = a.z; f[3] = a.w;
        f[4] = b.x; f[5] = b.y; f[6] = b.z; f[7] = b.w;
    } else {
        uint4 v = *(const uint4*)((const unsigned short*)p + off);
        const unsigned int* w = (const unsigned int*)&v;
#pragma unroll
        for (int i = 0; i < 4; i++) {
            f[2 * i]     = __uint_as_float(w[i] << 16);
            f[2 * i + 1] = __uint_as_float(w[i] & 0xffff0000u);
        }
    }
}
__device__ __forceinline__ int read_idx(const void* p, int is64, int e) {
    return is64 ? (int)((const long long*)p)[e] : ((const int*)p)[e];
}

// ---------------- init: zero counters + dtype detect ----------------
__device__ __forceinline__ int is_fp32_wave(const unsigned int* p, int lane) {
    unsigned w = p[lane];
    unsigned low = w & 0xFFFFu;
    unsigned ex = (low >> 7) & 0xFFu;
    bool hit = (ex >= 90u && ex <= 140u) || low == 0u || low == 0x8000u;
    unsigned long long m = __ballot(hit);
    return (2 * __popcll(m) < 64) ? 1 : 0;
}
__global__ void init_kernel(const unsigned int* __restrict__ src,
                            const unsigned int* __restrict__ feat,
                            const unsigned int* __restrict__ wn,
                            const unsigned int* __restrict__ wsm,
                            const unsigned int* __restrict__ bias,
                            int* __restrict__ flags, int* __restrict__ cnt, int Z) {
    int i = blockIdx.x * blockDim.x + threadIdx.x;
    if (i < Z) cnt[i] = 0;
    if (blockIdx.x == 0 && threadIdx.x < 64) {
        int lane = threadIdx.x;
        unsigned long long m = __ballot(src[1 + 2 * lane] != 0u);
        int f1 = is_fp32_wave(feat, lane);
        int f2 = is_fp32_wave(wn, lane);
        int f3 = is_fp32_wave(wsm, lane);
        int f4 = is_fp32_wave(bias, lane);
        if (lane == 0) {
            flags[0] = (m == 0ull) ? 1 : 0;
            flags[1] = f1; flags[2] = f2; flags[3] = f3; flags[4] = f4;
        }
    }
}

// ---------------- pass 1: radix partition by dst>>6, 1024 threads ----------------
// Grid = [0,eb) edge blocks | [eb,eb+cb) feat convert | [eb+cb,+4) W pre-pack.
// W pre-pack writes W_cat as 4096 ready-to-MFMA bf16 B-fragments (64 KB) so
// ggemm needs NO 64KB LDS union (round-7 lesson: that union capped occupancy
// at 15% and cost +23us on the latency-bound gather).
__global__ __launch_bounds__(1024) void part_kernel(
    const void* __restrict__ srcv, const void* __restrict__ dstv,
    const int* __restrict__ flags, int* __restrict__ gcnt,
    unsigned* __restrict__ pbuf,
    const float* __restrict__ featf, unsigned short* __restrict__ wsbf,
    const void* __restrict__ Wn, const void* __restrict__ Ws,
    unsigned short* __restrict__ wfrag,
    int E, int N, int eblocks, int total8, int nparts, int cstride, int cb) {
    __shared__ int hist[1024];
    __shared__ int bstart[1024];
    __shared__ int gbase[1024];
    __shared__ int tsum[1024];
    __shared__ unsigned stage[CHUNK];

    int b = blockIdx.x;
    int t = threadIdx.x;

    if (b >= eblocks + cb) {         // W pre-pack: 4 blocks x 1024 threads = 4096 frags
        int f = (b - eblocks - cb) * 1024 + t;
        if (f < 4096) {
            int tj = f >> 9, ks = (f >> 6) & 7, ln = f & 63;
            int j = tj * 16 + (ln & 15);
            int kk = ks * 32 + (ln >> 4) * 8;
            float w[8];
            if (kk < DIM) load8(Ws, flags[3], (size_t)j * DIM + kk, w);
            else          load8(Wn, flags[2], (size_t)j * DIM + (kk - DIM), w);
            unsigned short u[8];
#pragma unroll
            for (int i = 0; i < 8; i++) u[i] = f2bf(w[i]);
            *(uint4*)(wfrag + (size_t)f * 8) = *(uint4*)u;
        }
        return;
    }
    if (b >= eblocks) {              // feat fp32 -> bf16 convert (grid-stride)
        if (!flags[1]) return;
        for (int i = (b - eblocks) * 1024 + t; i < total8; i += cstride) {
            size_t e = (size_t)i * 8;
            float4 a = *(const float4*)(featf + e);
            float4 bb = *(const float4*)(featf + e + 4);
            unsigned short u[8] = {f2bf(a.x), f2bf(a.y), f2bf(a.z), f2bf(a.w),
                                   f2bf(bb.x), f2bf(bb.y), f2bf(bb.z), f2bf(bb.w)};
            *(uint4*)(wsbf + e) = *(uint4*)u;
        }
        return;
    }

    int is64 = flags[0];
    hist[t] = 0;
    __syncthreads();

    // load + pack + LDS histogram
    unsigned v[EPT2];
    int base = b * CHUNK;
#pragma unroll
    for (int j = 0; j < EPT2; j++) {
        int e = base + j * 1024 + t;
        unsigned val = 0xFFFFFFFFu;
        if (e < E) {
            int s = read_idx(srcv, is64, e);
            int d = read_idx(dstv, is64, e);
            if ((unsigned)s < (unsigned)N && (unsigned)d < (unsigned)N)
                val = ((unsigned)d << 16) | (unsigned)s;
        }
        v[j] = val;
        if (val != 0xFFFFFFFFu) atomicAdd(&hist[val >> 22], 1);
    }
    __syncthreads();

    // inclusive scan over 1024 (1 bin/thread; t>=nparts contributes 0)
    int h = (t < nparts) ? hist[t] : 0;
    tsum[t] = h;
    __syncthreads();
    for (int off = 1; off < 1024; off <<= 1) {
        int x = (t >= off) ? tsum[t - off] : 0;
        __syncthreads();
        tsum[t] += x;
        __syncthreads();
    }
    int tot = tsum[1023];
    int run = (t > 0) ? tsum[t - 1] : 0;     // exclusive prefix
    if (t < nparts) {
        bstart[t] = run;
        hist[t] = run;                        // cursor
        gbase[t] = h ? atomicAdd(&gcnt[t], h) : 0;   // reserve global run
    }
    __syncthreads();

    // reorder through LDS
#pragma unroll
    for (int j = 0; j < EPT2; j++) {
        unsigned val = v[j];
        if (val != 0xFFFFFFFFu) {
            int bin = val >> 22;
            int pos = atomicAdd(&hist[bin], 1);
            stage[pos] = val;
        }
    }
    __syncthreads();

    // coalesced per-run copy-out
    for (int pp = t; pp < tot; pp += 1024) {
        unsigned val = stage[pp];
        int bin = val >> 22;
        unsigned off = (unsigned)(gbase[bin] + (pp - bstart[bin]));
        if (off < PCAP) pbuf[(size_t)bin * PCAP + off] = val;
    }
}

// ---------------- pass 2: merged list-build + gather + MFMA GEMM ----------------
// One block per partition (64 nodes, 4 waves). LDS = 8.5 KB only (cnt+list) —
// W fragments come pre-packed from global (L2-resident, coalesced) so the
// gather phase keeps high occupancy (round-7: 64KB LDS union -> 15% occ, -23us).
// hn is written and re-read by the SAME wave -> race-free, L2-hot.
__global__ __launch_bounds__(256) void ggemm_kernel(
    const void* __restrict__ feat, const unsigned short* __restrict__ wsbf,
    const unsigned* __restrict__ pbuf, const int* __restrict__ gcnt,
    const unsigned short* __restrict__ wfrag,
    const void* __restrict__ bias, void* __restrict__ out,
    int N, const int* __restrict__ flags) {
    __shared__ int cntp[64];
    __shared__ unsigned short list[64][64];

    int t = threadIdx.x;
    int lane = t & 63;
    int wv = t >> 6;
    int p = blockIdx.x;
    int nbase = p << 6;
    int feat32 = flags[1], bs32 = flags[4];
    const unsigned short* sb = feat32 ? wsbf : (const unsigned short*)feat;
    char* hbase = (char*)out;
    size_t hrow = feat32 ? 512 : 256;
    size_t hoff = feat32 ? 256 : 0;

    // phase 1: zero counters
    if (t < 64) cntp[t] = 0;
    __syncthreads();

    // phase 2: build per-node lists (LDS atomics)
    int ec = gcnt[p];
    if (ec > PCAP) ec = PCAP;
    for (int i = t; i < ec; i += 256) {
        unsigned val = pbuf[(size_t)p * PCAP + i];
        int local = (int)(val >> 16) - nbase;      // 0..63 by construction
        int pos = atomicAdd(&cntp[local], 1);
        if (pos < 64) list[local][pos] = (unsigned short)(val & 0xFFFFu);
    }
    __syncthreads();

    // phase 3: widened gather (dwordx4; each 16-lane group a different row)
    int grp = lane >> 4;
    int li = lane & 15;
    for (int q = 0; q < 16; q++) {
        int local = wv * 16 + q;
        int node = nbase + local;
        if (node >= N) break;
        int deg = cntp[local];
        int use = deg < 64 ? deg : 64;

        float acc[8];
#pragma unroll
        for (int i = 0; i < 8; i++) acc[i] = 0.f;

        for (int k = 0; k < use; k += 16) {
            uint4 v[4];
            float wgt[4];
#pragma unroll
            for (int j = 0; j < 4; j++) {
                int r = k + j * 4 + grp;
                wgt[j] = (r < use) ? 1.0f : 0.0f;
                int rc = (r < use) ? r : (use - 1);   // clamp: dup load hits cache
                int s = list[local][rc];
                v[j] = *(const uint4*)(sb + (size_t)s * DIM + li * 8);
            }
#pragma unroll
            for (int j = 0; j < 4; j++) {
                const unsigned* w = (const unsigned*)&v[j];
#pragma unroll
                for (int i = 0; i < 4; i++) {
                    acc[2 * i]     = fmaf(wgt[j], __uint_as_float(w[i] << 16), acc[2 * i]);
                    acc[2 * i + 1] = fmaf(wgt[j], __uint_as_float(w[i] & 0xffff0000u), acc[2 * i + 1]);
                }
            }
        }
#pragma unroll
        for (int i = 0; i < 8; i++) {
            acc[i] += __shfl_xor(acc[i], 16);
            acc[i] += __shfl_xor(acc[i], 32);
        }
        float rd = 1.0f / fmaxf((float)deg, 1.0f);
        if (grp == 0) {
            unsigned short u[8];
#pragma unroll
            for (int i = 0; i < 8; i++) u[i] = f2bf(acc[i] * rd);
            *(uint4*)(hbase + (size_t)node * hrow + hoff + (size_t)li * 16) = *(uint4*)u;
        }
    }
    __syncthreads();   // hn stores drained (barrier implies vmcnt 0)

    // phase 4: GEMM — wave wv handles tile rows [nbase+wv*16, +16)
    const bf16x8* bfrag = (const bf16x8*)wfrag;   // global, L2-resident
    int quad = lane >> 4;

    float bcol[8];
#pragma unroll
    for (int tj = 0; tj < 8; tj++) {
        int col = tj * 16 + (lane & 15);
        bcol[tj] = bs32 ? ((const float*)bias)[col]
                        : bfbits(((const unsigned short*)bias)[col]);
    }

    int tb = nbase + wv * 16;
    int arow = tb + (lane & 15);
    if (arow >= N) arow = N - 1;

    bf16x8 afr[8];
#pragma unroll
    for (int ks = 0; ks < 4; ks++) {        // self (bf16: native or wsbf)
        int kk = ks * 32 + quad * 8;
        afr[ks] = *(const bf16x8*)(sb + (size_t)arow * DIM + kk);
    }
#pragma unroll
    for (int ks = 4; ks < 8; ks++) {        // neigh scratch in out (L2-hot)
        int kk = (ks - 4) * 32 + quad * 8;
        afr[ks] = *(const bf16x8*)(hbase + (size_t)arow * hrow + hoff + (size_t)kk * 2);
    }

    f32x4 acc[8];
#pragma unroll
    for (int tj = 0; tj < 8; tj++)
        acc[tj] = (f32x4){bcol[tj], bcol[tj], bcol[tj], bcol[tj]};

#pragma unroll
    for (int tj = 0; tj < 8; tj++) {
#pragma unroll
        for (int ks = 0; ks < 8; ks++) {
            acc[tj] = __builtin_amdgcn_mfma_f32_16x16x32_bf16(
                afr[ks], bfrag[(tj * 8 + ks) * 64 + lane], acc[tj], 0, 0, 0);
        }
    }

#pragma unroll
    for (int tj = 0; tj < 8; tj++) {
        int col = tj * 16 + (lane & 15);
#pragma unroll
        for (int r = 0; r < 4; r++) {
            int row = tb + quad * 4 + r;
            if (row < N) {
                size_t idx = (size_t)row * DIM + col;
                if (feat32) ((float*)out)[idx] = acc[tj][r];
                else ((unsigned short*)out)[idx] = f2bf(acc[tj][r]);
            }
        }
    }
}

// ---------------- fallback: round-0 bucketing (device atomics) ----------------
__global__ void buckcvt_kernel(const void* __restrict__ srcv, const void* __restrict__ dstv,
                               const int* __restrict__ flags, int* __restrict__ cnt,
                               unsigned short* __restrict__ b16, int* __restrict__ b32,
                               const float* __restrict__ featf,
                               unsigned short* __restrict__ wsbf,
                               int E, int N, int eblocks, int total8, int use16, int ws_ok) {
    int b = blockIdx.x;
    if (b < eblocks) {
        int e = b * 256 + threadIdx.x;
        if (e >= E) return;
        int is64 = flags[0];
        int s = read_idx(srcv, is64, e);
        int d = read_idx(dstv, is64, e);
        if ((unsigned)s >= (unsigned)N || (unsigned)d >= (unsigned)N) return;
        int pos = atomicAdd(&cnt[d], 1);
        if (pos < BK) {
            if (use16) b16[(size_t)d * BK + pos] = (unsigned short)s;
            else       b32[(size_t)d * BK + pos] = s;
        }
    } else {
        if (!flags[1] || !ws_ok) return;
        int i = (b - eblocks) * 256 + threadIdx.x;
        if (i >= total8) return;
        size_t e = (size_t)i * 8;
        float4 a = *(const float4*)(featf + e);
        float4 bb = *(const float4*)(featf + e + 4);
        unsigned short u[8] = {f2bf(a.x), f2bf(a.y), f2bf(a.z), f2bf(a.w),
                               f2bf(bb.x), f2bf(bb.y), f2bf(bb.z), f2bf(bb.w)};
        *(uint4*)(wsbf + e) = *(uint4*)u;
    }
}

__global__ __launch_bounds__(256) void gather_kernel(
    const void* __restrict__ feat, const unsigned short* __restrict__ wsbf,
    const unsigned short* __restrict__ b16, const int* __restrict__ b32,
    const int* __restrict__ cnt, void* __restrict__ dout,
    int N, const int* __restrict__ flags, int use16, int ws_ok) {
    int t = threadIdx.x;
    int lane = t & 63;
    int wv = t >> 6;
    int node = blockIdx.x * 4 + wv;
    if (node >= N) return;
    int feat32 = flags[1];
    int bfmode = (!feat32) || ws_ok;
    const unsigned short* sb = feat32 ? wsbf : (const unsigned short*)feat;
    const float* ff = (const float*)feat;

    int deg = __builtin_amdgcn_readfirstlane(cnt[node]);
    int use = deg < BK ? deg : BK;
    int idxv;
    if (use16) idxv = b16[(size_t)node * BK + (lane < use ? lane : 0)];
    else       idxv = b32[(size_t)node * BK + (lane < use ? lane : 0)];

    float a0 = 0.f, a1 = 0.f;
    int k = 0;
    if (bfmode) {
        for (; k + 8 <= use; k += 8) {
            int ss[8];
#pragma unroll
            for (int j = 0; j < 8; j++) ss[j] = __shfl(idxv, k + j);
            unsigned uu[8];
#pragma unroll
            for (int j = 0; j < 8; j++)
                uu[j] = *(const unsigned*)(sb + (size_t)ss[j] * DIM + lane * 2);
#pragma unroll
            for (int j = 0; j < 8; j++) {
                a0 += bfbits((unsigned short)uu[j]);
                a1 += bfbits((unsigned short)(uu[j] >> 16));
            }
        }
        for (; k < use; k++) {
            int s = __shfl(idxv, k);
            unsigned u = *(const unsigned*)(sb + (size_t)s * DIM + lane * 2);
            a0 += bfbits((unsigned short)u);
            a1 += bfbits((unsigned short)(u >> 16));
        }
    } else {
        for (; k + 4 <= use; k += 4) {
            int s0 = __shfl(idxv, k),     s1 = __shfl(idxv, k + 1);
            int s2 = __shfl(idxv, k + 2), s3 = __shfl(idxv, k + 3);
            float2 v0 = *(const float2*)(ff + (size_t)s0 * DIM + lane * 2);
            float2 v1 = *(const float2*)(ff + (size_t)s1 * DIM + lane * 2);
            float2 v2 = *(const float2*)(ff + (size_t)s2 * DIM + lane * 2);
            float2 v3 = *(const float2*)(ff + (size_t)s3 * DIM + lane * 2);
            a0 += (v0.x + v1.x) + (v2.x + v3.x);
            a1 += (v0.y + v1.y) + (v2.y + v3.y);
        }
        for (; k < use; k++) {
            int s = __shfl(idxv, k);
            float2 v = *(const float2*)(ff + (size_t)s * DIM + lane * 2);
            a0 += v.x; a1 += v.y;
        }
    }

    float rd = 1.0f / fmaxf((float)deg, 1.0f);
    unsigned up = ((unsigned)f2bf(a1 * rd) << 16) | (unsigned)f2bf(a0 * rd);
    size_t ob = feat32 ? ((size_t)node * 512 + 256 + (size_t)lane * 4)
                       : ((size_t)node * 256 + (size_t)lane * 4);
    *(unsigned*)((char*)dout + ob) = up;
}

// ---------------- fallback MFMA GEMM (dual-tile) ----------------
#define TPW 2
__global__ __launch_bounds__(256) void gemm_kernel(
    const void* __restrict__ feat, const unsigned short* __restrict__ wsbf,
    const void* __restrict__ Wn, const void* __restrict__ Ws,
    const void* __restrict__ bias, void* __restrict__ out,
    int N, const int* __restrict__ flags, int ws_ok) {
    __shared__ short ldsb[4096 * 8];   // 64 KB

    int t = threadIdx.x;
    int lane = t & 63;
    int wv = t >> 6;
    int feat32 = flags[1], wn32 = flags[2], ws32 = flags[3], bs32 = flags[4];
    int bfmode = (!feat32) || ws_ok;

    for (int f = t; f < 4096; f += 256) {
        int tj = f >> 9, ks = (f >> 6) & 7, ln = f & 63;
        int j = tj * 16 + (ln & 15);
        int kk = ks * 32 + (ln >> 4) * 8;
        float w[8];
        if (kk < DIM) load8(Ws, ws32, (size_t)j * DIM + kk, w);
        else          load8(Wn, wn32, (size_t)j * DIM + (kk - DIM), w);
        unsigned short u[8];
#pragma unroll
        for (int i = 0; i < 8; i++) u[i] = f2bf(w[i]);
        *(uint4*)(ldsb + (size_t)f * 8) = *(uint4*)u;
    }
    __syncthreads();

    const bf16x8* bfrag = (const bf16x8*)ldsb;

    float bcol[8];
#pragma unroll
    for (int tj = 0; tj < 8; tj++) {
        int col = tj * 16 + (lane & 15);
        bcol[tj] = bs32 ? ((const float*)bias)[col]
                        : bfbits(((const unsigned short*)bias)[col]);
    }

    int quad = lane >> 4;
    int NT = (N + 15) >> 4;
    int gw = blockIdx.x * 4 + wv;

    const unsigned short* sb = feat32 ? wsbf : (const unsigned short*)feat;
    const char* hbase = (const char*)out;
    size_t hrow = feat32 ? 512 : 256;
    size_t hoff = feat32 ? 256 : 0;

    int tile0 = gw * TPW;
    int tile1 = tile0 + 1;
    if (tile0 >= NT) return;
    int has1 = (tile1 < NT);
    int tb0 = tile0 * 16;
    int tb1 = has1 ? tile1 * 16 : tb0;

    int arow0 = tb0 + (lane & 15); if (arow0 >= N) arow0 = N - 1;
    int arow1 = tb1 + (lane & 15); if (arow1 >= N) arow1 = N - 1;

    bf16x8 afr0[8], afr1[8];
#pragma unroll
    for (int ks = 0; ks < 4; ks++) {
        int kk = ks * 32 + quad * 8;
        if (bfmode) {
            afr0[ks] = *(const bf16x8*)(sb + (size_t)arow0 * DIM + kk);
            afr1[ks] = *(const bf16x8*)(sb + (size_t)arow1 * DIM + kk);
        } else {
            float av[8]; unsigned short u[8];
            load8(feat, 1, (size_t)arow0 * DIM + kk, av);
#pragma unroll
            for (int i = 0; i < 8; i++) u[i] = f2bf(av[i]);
            afr0[ks] = *(bf16x8*)u;
            load8(feat, 1, (size_t)arow1 * DIM + kk, av);
#pragma unroll
            for (int i = 0; i < 8; i++) u[i] = f2bf(av[i]);
            afr1[ks] = *(bf16x8*)u;
        }
    }
#pragma unroll
    for (int ks = 4; ks < 8; ks++) {
        int kk = (ks - 4) * 32 + quad * 8;
        afr0[ks] = *(const bf16x8*)(hbase + (size_t)arow0 * hrow + hoff + (size_t)kk * 2);
        afr1[ks] = *(const bf16x8*)(hbase + (size_t)arow1 * hrow + hoff + (size_t)kk * 2);
    }

    f32x4 acc0[8], acc1[8];
#pragma unroll
    for (int tj = 0; tj < 8; tj++) {
        acc0[tj] = (f32x4){bcol[tj], bcol[tj], bcol[tj], bcol[tj]};
        acc1[tj] = acc0[tj];
    }

#pragma unroll
    for (int tj = 0; tj < 8; tj++) {
#pragma unroll
        for (int ks = 0; ks < 8; ks++) {
            bf16x8 bf = bfrag[(tj * 8 + ks) * 64 + lane];
            acc0[tj] = __builtin_amdgcn_mfma_f32_16x16x32_bf16(afr0[ks], bf, acc0[tj], 0, 0, 0);
            acc1[tj] = __builtin_amdgcn_mfma_f32_16x16x32_bf16(afr1[ks], bf, acc1[tj], 0, 0, 0);
        }
    }

#pragma unroll
    for (int tj = 0; tj < 8; tj++) {
        int col = tj * 16 + (lane & 15);
#pragma unroll
        for (int r = 0; r < 4; r++) {
            int row0 = tb0 + quad * 4 + r;
            if (row0 < N) {
                size_t idx = (size_t)row0 * DIM + col;
                if (feat32) ((float*)out)[idx] = acc0[tj][r];
                else ((unsigned short*)out)[idx] = f2bf(acc0[tj][r]);
            }
            if (has1) {
                int row1 = tb1 + quad * 4 + r;
                if (row1 < N) {
                    size_t idx = (size_t)row1 * DIM + col;
                    if (feat32) ((float*)out)[idx] = acc1[tj][r];
                    else ((unsigned short*)out)[idx] = f2bf(acc1[tj][r]);
                }
            }
        }
    }
}

extern "C" void kernel_launch(void* const* d_in, const int* in_sizes, int n_in,
                              void* d_out, int out_size, void* d_ws, size_t ws_size,
                              hipStream_t stream) {
    const void* feat = d_in[0];
    const void* src  = d_in[1];
    const void* dst  = d_in[2];
    const void* Wn   = d_in[3];
    const void* Ws   = d_in[4];
    const void* bias = d_in[5];

    const int N = in_sizes[0] / DIM;
    const int E = in_sizes[1];
    const int use16 = (N <= 65535) ? 1 : 0;
    const int total8 = N * DIM / 8;
    int* flags = (int*)d_ws;

    // fast-path: flags | gcnt | pbuf | wsbf | wfrag(64KB)
    const int nparts = (N + 63) >> 6;
    size_t pbuf_off = (64 + (size_t)nparts * 4 + 255) & ~(size_t)255;
    size_t wsf_off  = (pbuf_off + (size_t)nparts * PCAP * 4 + 255) & ~(size_t)255;
    size_t wfg_off  = (wsf_off + (size_t)N * DIM * 2 + 255) & ~(size_t)255;
    size_t need_f   = wfg_off + 65536;
    const int FAST = (use16 && nparts <= 1024 && ws_size >= need_f) ? 1 : 0;

    if (FAST) {
        int* gcnt = (int*)((char*)d_ws + 64);
        unsigned* pbuf = (unsigned*)((char*)d_ws + pbuf_off);
        unsigned short* wsbf = (unsigned short*)((char*)d_ws + wsf_off);
        unsigned short* wfrag = (unsigned short*)((char*)d_ws + wfg_off);

        init_kernel<<<(nparts + 255) / 256, 256, 0, stream>>>(
            (const unsigned int*)src, (const unsigned int*)feat, (const unsigned int*)Wn,
            (const unsigned int*)Ws, (const unsigned int*)bias, flags, gcnt, nparts);

        int eb = (E + CHUNK - 1) / CHUNK;
        int cb = (total8 + 1023) / 1024;
        if (cb > 1024) cb = 1024;                 // grid-stride convert
        part_kernel<<<eb + cb + 4, 1024, 0, stream>>>(
            src, dst, flags, gcnt, pbuf, (const float*)feat, wsbf,
            Wn, Ws, wfrag, E, N, eb, total8, nparts, cb * 1024, cb);

        ggemm_kernel<<<nparts, 256, 0, stream>>>(
            feat, wsbf, pbuf, gcnt, wfrag, bias, d_out, N, flags);
        return;
    }

    // ---------- fallback: round-0 proven path ----------
    const size_t esz = use16 ? 2 : 4;
    int* cnt = flags + 16;
    unsigned short* b16 = (unsigned short*)(cnt + N);
    int* b32 = (int*)(cnt + N);
    size_t bucket_bytes = (size_t)N * BK * esz;
    size_t bf_off = (64 + (size_t)N * 4 + bucket_bytes + 15) & ~(size_t)15;
    unsigned short* wsbf = (unsigned short*)((char*)d_ws + bf_off);
    size_t need = bf_off + (size_t)N * DIM * 2;
    int ws_ok = (ws_size >= need) ? 1 : 0;

    init_kernel<<<(N + 255) / 256, 256, 0, stream>>>(
        (const unsigned int*)src, (const unsigned int*)feat, (const unsigned int*)Wn,
        (const unsigned int*)Ws, (const unsigned int*)bias, flags, cnt, N);

    int eblocks = (E + 255) / 256;
    int cblocks = ws_ok ? (total8 + 255) / 256 : 0;
    buckcvt_kernel<<<eblocks + cblocks, 256, 0, stream>>>(
        src, dst, flags, cnt, b16, b32, (const float*)feat, wsbf,
        E, N, eblocks, total8, use16, ws_ok);

    gather_kernel<<<(N + 3) / 4, 256, 0, stream>>>(
        feat, wsbf, b16, b32, cnt, d_out, N, flags, use16, ws_ok);

    int NT = (N + 15) / 16;
    int gwaves = (NT + TPW - 1) / TPW;
    gemm_kernel<<<(gwaves + 3) / 4, 256, 0, stream>>>(
        feat, wsbf, Wn, Ws, bias, d_out, N, flags, ws_ok);
}